// Round 8
// baseline (303.607 us; speedup 1.0000x reference)
//
#include <hip/hip_runtime.h>

// Problem: B=4, S=2048, D=1024, H=16, W=64.
// Inputs fp32, output fp32; compute in bf16 MFMA.
#define B_ 4
#define S_ 2048
#define D_ 1024
#define H_ 16
#define W_ 64

typedef __attribute__((ext_vector_type(8))) __bf16 bf16x8;
typedef __attribute__((ext_vector_type(4))) __bf16 bf16x4;
typedef __attribute__((ext_vector_type(4))) float f32x4;

static __device__ __forceinline__ void gload_lds16(const void* g, void* l) {
  __builtin_amdgcn_global_load_lds((const __attribute__((address_space(1))) void*)g,
                                   (__attribute__((address_space(3))) void*)l,
                                   16, 0, 0);
}

#define MFMA16(a, b, c) __builtin_amdgcn_mfma_f32_16x16x32_bf16((a), (b), (c), 0, 0, 0)

// Raw v_exp_f32 (2^x). exp2f libcall carries non-fast-math range checks (R6 lesson).
#if __has_builtin(__builtin_amdgcn_exp2f)
#define EXP2(x) __builtin_amdgcn_exp2f(x)
#else
#define EXP2(x) __expf((x) * 0.6931472f)
#endif

// ---------------------------------------------------------------------------
// Kernel 1: convert x (fp32) -> bf16 scratch. 8 elems/thread.
// ---------------------------------------------------------------------------
__global__ __launch_bounds__(256) void convx(const float* __restrict__ x,
                                             __bf16* __restrict__ xb) {
  const size_t i = ((size_t)blockIdx.x * 256 + threadIdx.x) * 8;
  const f32x4 v0 = *(const f32x4*)(x + i);
  const f32x4 v1 = *(const f32x4*)(x + i + 4);
  bf16x8 v;
#pragma unroll
  for (int k = 0; k < 4; k++) { v[k] = (__bf16)v0[k]; v[4 + k] = (__bf16)v1[k]; }
  *(bf16x8*)(xb + i) = v;
}

// ---------------------------------------------------------------------------
// Kernel 2: weight transpose+convert W[k][n] (fp32) -> T[n][k] bf16
// ---------------------------------------------------------------------------
__global__ __launch_bounds__(256) void wtrans(
    const float* __restrict__ Wq, const float* __restrict__ Wk, const float* __restrict__ Wv,
    __bf16* __restrict__ Tq, __bf16* __restrict__ Tk, __bf16* __restrict__ Tv) {
  __shared__ __bf16 t[64][65];
  const int z = blockIdx.z;
  const float* W = (z == 0) ? Wq : (z == 1) ? Wk : Wv;
  __bf16* T = (z == 0) ? Tq : (z == 1) ? Tk : Tv;
  const int n0 = blockIdx.x * 64, k0 = blockIdx.y * 64;
  const int row = threadIdx.x >> 2, c0 = (threadIdx.x & 3) * 16;
#pragma unroll
  for (int i = 0; i < 16; i++)
    t[row][c0 + i] = (__bf16)W[(size_t)(k0 + row) * D_ + n0 + c0 + i];
  __syncthreads();
#pragma unroll
  for (int i = 0; i < 16; i++) T[(size_t)(n0 + row) * D_ + k0 + c0 + i] = t[c0 + i][row];
}

// ---------------------------------------------------------------------------
// Kernel 3: bias convert fp32 -> bf16 in ws (3 x 1024)
// ---------------------------------------------------------------------------
__global__ __launch_bounds__(256) void convb(
    const float* __restrict__ bq, const float* __restrict__ bk, const float* __restrict__ bv,
    __bf16* __restrict__ dst) {
  const int z = blockIdx.x;
  const float* src = (z == 0) ? bq : (z == 1) ? bk : bv;
  const int i = threadIdx.x * 4;
#pragma unroll
  for (int k = 0; k < 4; k++) dst[z * 1024 + i + k] = (__bf16)src[i + k];
}

// ---------------------------------------------------------------------------
// Kernel 4: fused QKV projection GEMM. K-loop = m97 structure; NEW epilogue:
//   C-tile staged through LDS in output-layout order, stores are coalesced
//   16B dwordx4 (was 64 scalar 2B stores / 8B stride-4KB stores).
//   Q scaled by 0.125*log2(e); Q,K written [B,H,S,64]; V written [B,H,64,S].
// ---------------------------------------------------------------------------
__global__ __launch_bounds__(256) void qkv_gemm(
    const __bf16* __restrict__ x,
    const __bf16* __restrict__ Tq, const __bf16* __restrict__ Tk, const __bf16* __restrict__ Tv,
    const __bf16* __restrict__ biasb,
    __bf16* __restrict__ Qo, __bf16* __restrict__ Ko, __bf16* __restrict__ Vto) {
  __shared__ __align__(16) __bf16 smem[8192];  // 16 KB: As|Bs during K-loop, Cs in epilogue
  __bf16* As = smem;
  __bf16* Bs = smem + 4096;
  const int tid = threadIdx.x, lane = tid & 63;
  const int wid = tid >> 6, wm = wid >> 1, wn = wid & 1;
  const int quad = lane >> 4, col = lane & 15;
  const int n0 = blockIdx.x * 128, m0 = blockIdx.y * 128, z = blockIdx.z;
  const __bf16* Wt = (z == 0) ? Tq : (z == 1) ? Tk : Tv;
  const __bf16* bias = biasb + z * 1024;

  f32x4 acc[4][4] = {};

  const int f1 = tid * 16, r1 = f1 >> 6, o1 = f1 & 63;
  const int f2 = f1 + 4096, r2 = f2 >> 6, o2 = f2 & 63;

  for (int kt = 0; kt < D_ / 32; ++kt) {
    const int k0 = kt * 32;
    __syncthreads();
    const char* ax = (const char*)x;
    gload_lds16(ax + ((size_t)(m0 + r1) * D_ + k0) * 2 + o1, (char*)As + f1);
    gload_lds16(ax + ((size_t)(m0 + r2) * D_ + k0) * 2 + o2, (char*)As + f2);
    const char* bx = (const char*)Wt;
    gload_lds16(bx + ((size_t)(n0 + r1) * D_ + k0) * 2 + o1, (char*)Bs + f1);
    gload_lds16(bx + ((size_t)(n0 + r2) * D_ + k0) * 2 + o2, (char*)Bs + f2);
    __syncthreads();

    bf16x8 a[4], bb[4];
#pragma unroll
    for (int i = 0; i < 4; i++)
      a[i] = *(const bf16x8*)(As + (wm * 64 + 16 * i + col) * 32 + quad * 8);
#pragma unroll
    for (int j = 0; j < 4; j++)
      bb[j] = *(const bf16x8*)(Bs + (wn * 64 + 16 * j + col) * 32 + quad * 8);
#pragma unroll
    for (int i = 0; i < 4; i++)
#pragma unroll
      for (int j = 0; j < 4; j++) acc[i][j] = MFMA16(a[i], bb[j], acc[i][j]);
  }

  __syncthreads();  // done reading As/Bs; smem becomes Cs

  const int bidx = m0 >> 11, sbase = m0 & 2047;  // tile never straddles batch
  // Q scale folds 1/sqrt(64) AND log2(e) so attn can use raw exp2.
  const float scale = (z == 0) ? 0.18033688f : 1.0f;

  if (z < 2) {
    __bf16* outp = (z == 0) ? Qo : Ko;
#pragma unroll
    for (int p = 0; p < 2; p++) {  // two 64-row (s) passes; waves wm==p write
      if (wm == p) {
#pragma unroll
        for (int j = 0; j < 4; j++) {
          const int n = wn * 64 + 16 * j + col;
          const float bval = (float)bias[n0 + n];
#pragma unroll
          for (int i = 0; i < 4; i++) {
            const int srow = 16 * i + quad * 4;
#pragma unroll
            for (int r = 0; r < 4; r++)
              smem[(srow + r) * 128 + n] = (__bf16)((acc[i][j][r] + bval) * scale);
          }
        }
      }
      __syncthreads();
      // linear read-back -> coalesced 16B stores (each thread: 64B contiguous)
#pragma unroll
      for (int c = 0; c < 4; c++) {
        const int e = tid * 32 + c * 8;
        const int srow = e >> 7, nn = e & 127;
        const int h = (n0 >> 6) + (nn >> 6), w = nn & 63;
        const bf16x8 v = *(const bf16x8*)(smem + e);
        *(bf16x8*)(outp + ((size_t)(bidx * H_ + h) * S_ + sbase + p * 64 + srow) * W_ + w) = v;
      }
      __syncthreads();
    }
  } else {
#pragma unroll
    for (int p = 0; p < 2; p++) {  // two 64-row (n) passes; waves wn==p write
      if (wn == p) {
#pragma unroll
        for (int j = 0; j < 4; j++) {
          const int nr = 16 * j + col;  // n-row within this half
          const float bval = (float)bias[n0 + wn * 64 + nr];
#pragma unroll
          for (int i = 0; i < 4; i++) {
            const int sl = wm * 64 + 16 * i + quad * 4;
            const int cc = sl >> 3;  // 16B chunk; XOR-swizzle vs n-row for banks
            bf16x4 pv;
#pragma unroll
            for (int r = 0; r < 4; r++) pv[r] = (__bf16)(acc[i][j][r] + bval);
            *(bf16x4*)(smem + nr * 128 + ((cc ^ (nr & 7)) << 3) + (sl & 7)) = pv;
          }
        }
      }
      __syncthreads();
#pragma unroll
      for (int c = 0; c < 4; c++) {
        const int e = tid * 32 + c * 8;
        const int nr = e >> 7, sl = e & 127;
        const int cc = sl >> 3;
        const bf16x8 v = *(const bf16x8*)(smem + nr * 128 + ((cc ^ (nr & 7)) << 3));
        const int ngl = n0 + p * 64 + nr;
        const int h = ngl >> 6, w = ngl & 63;
        *(bf16x8*)(Vto + ((size_t)(bidx * H_ + h) * W_ + w) * S_ + sbase + sl) = v;
      }
      __syncthreads();
    }
  }
}

// ---------------------------------------------------------------------------
// Kernel 5: flash attention, S^T formulation, XOR-swizzled K/V LDS,
//   DOUBLE-BUFFERED K/V staging with ONE barrier per iter: prefetch tile t+1
//   right after the barrier, compute tile t -> the vmcnt drain at the next
//   barrier waits on loads issued a full compute-phase earlier (~free).
// ---------------------------------------------------------------------------
__global__ __launch_bounds__(256) void attn(
    const __bf16* __restrict__ Q, const __bf16* __restrict__ K,
    const __bf16* __restrict__ Vt, const int* __restrict__ mask,
    float* __restrict__ out) {
  __shared__ __align__(16) __bf16 Kl[2][64 * 64];  // [key][w], chunk-swizzled
  __shared__ __align__(16) __bf16 Vl[2][64 * 64];  // [w][key], chunk-swizzled
  __shared__ __align__(16) __bf16 Pl[4][32 * 72];  // per-wave P[q][key], stride 72
  __shared__ float Ml[2][64];                      // additive mask * log2e
  __shared__ int Mflag[2];                         // 1 = tile mask all ones

  const int tid = threadIdx.x, lane = tid & 63, wid = tid >> 6;
  const int quad = lane >> 4, col = lane & 15;
  const int bh = blockIdx.y, b = bh >> 4, h = bh & 15;
  const int qbase = blockIdx.x * 128 + wid * 32;
  const int sw = col & 7;

  // Q B-fragments (lane n=col holds Q[q][k=quad*8+j], kk chunks): qf[qg][kk]
  bf16x8 qf[2][2];
#pragma unroll
  for (int qg = 0; qg < 2; qg++) {
    const __bf16* qp = Q + ((size_t)bh * S_ + qbase + qg * 16 + col) * W_ + quad * 8;
    qf[qg][0] = *(const bf16x8*)qp;
    qf[qg][1] = *(const bf16x8*)(qp + 32);
  }

  f32x4 oacc[2][4] = {};
  float lrow[2] = {0.f, 0.f};

  // staging lanes: flat f -> row r (128B), chunk c; fetch global chunk c^(r&7)
  const int f1 = tid * 16, r1 = f1 >> 7, c1 = (f1 >> 4) & 7;
  const int f2 = f1 + 4096, r2 = f2 >> 7, c2 = (f2 >> 4) & 7;
  const int s1 = (c1 ^ (r1 & 7)) << 4, s2 = (c2 ^ (r2 & 7)) << 4;

  const char* kgb = (const char*)(K + (size_t)bh * S_ * W_);
  const char* vgb = (const char*)(Vt + (size_t)bh * W_ * S_);
  __bf16* Pw = Pl[wid];

#define STAGE(buf, kt_)                                                        \
  do {                                                                         \
    const int k0_ = (kt_) * 64;                                                \
    const char* kg_ = kgb + (size_t)k0_ * 128;                                 \
    gload_lds16(kg_ + (size_t)r1 * 128 + s1, (char*)Kl[buf] + f1);             \
    gload_lds16(kg_ + (size_t)r2 * 128 + s2, (char*)Kl[buf] + f2);             \
    const char* vg_ = vgb + (size_t)k0_ * 2;                                   \
    gload_lds16(vg_ + (size_t)r1 * (S_ * 2) + s1, (char*)Vl[buf] + f1);        \
    gload_lds16(vg_ + (size_t)r2 * (S_ * 2) + s2, (char*)Vl[buf] + f2);        \
    if (tid < 64) {                                                            \
      const int m_ = mask[b * S_ + k0_ + tid];                                 \
      Ml[buf][tid] = -14426.95f * (1.0f - (float)m_);                          \
      const unsigned long long bal_ = __ballot(m_ != 0);                       \
      if (tid == 0) Mflag[buf] = (~bal_ == 0ull) ? 1 : 0;                      \
    }                                                                          \
  } while (0)

  STAGE(0, 0);

  for (int kt = 0; kt < S_ / 64; ++kt) {
    const int cur = kt & 1;
    __syncthreads();  // drains vmcnt: tile kt ready; prev tile's readers done
    if (kt + 1 < S_ / 64) STAGE(1 - cur, kt + 1);  // async prefetch

    const __bf16* Klc = Kl[cur];
    const __bf16* Vlc = Vl[cur];

    // St = K.Q^T : A-frag = K rows (m=key=16mt+col), B-frag = qf
    f32x4 sacc[2][4] = {};
#pragma unroll
    for (int mt = 0; mt < 4; mt++) {
      const __bf16* kr = Klc + (16 * mt + col) * 64;
      const bf16x8 ka0 = *(const bf16x8*)(kr + ((quad ^ sw) << 3));
      const bf16x8 ka1 = *(const bf16x8*)(kr + (((4 + quad) ^ sw) << 3));
#pragma unroll
      for (int qg = 0; qg < 2; qg++) {
        sacc[qg][mt] = MFMA16(ka0, qf[qg][0], sacc[qg][mt]);
        sacc[qg][mt] = MFMA16(ka1, qf[qg][1], sacc[qg][mt]);
      }
    }
    // additive mask only when some key is masked (wave-uniform branch)
    const int allone = __builtin_amdgcn_readfirstlane(Mflag[cur]);
    if (!allone) {
      f32x4 mAdd[4];
#pragma unroll
      for (int mt = 0; mt < 4; mt++) mAdd[mt] = *(const f32x4*)(&Ml[cur][16 * mt + quad * 4]);
#pragma unroll
      for (int qg = 0; qg < 2; qg++)
#pragma unroll
        for (int mt = 0; mt < 4; mt++)
#pragma unroll
          for (int r = 0; r < 4; r++) sacc[qg][mt][r] += mAdd[mt][r];
    }

    // plain softmax partial: p = exp2(s') via raw v_exp_f32; vector l-sum
#pragma unroll
    for (int qg = 0; qg < 2; qg++) {
      f32x4 vsum = {0.f, 0.f, 0.f, 0.f};
#pragma unroll
      for (int mt = 0; mt < 4; mt++) {
#pragma unroll
        for (int r = 0; r < 4; r++) sacc[qg][mt][r] = EXP2(sacc[qg][mt][r]);
        vsum += sacc[qg][mt];
      }
      float sum = (vsum[0] + vsum[1]) + (vsum[2] + vsum[3]);
      sum += __shfl_xor(sum, 16, 64);
      sum += __shfl_xor(sum, 32, 64);
      lrow[qg] += sum;
      // P[q][key]: 4 consecutive keys per (mt) -> ds_write_b64
#pragma unroll
      for (int mt = 0; mt < 4; mt++) {
        bf16x4 pv;
#pragma unroll
        for (int r = 0; r < 4; r++) pv[r] = (__bf16)sacc[qg][mt][r];
        *(bf16x4*)(Pw + (qg * 16 + col) * 72 + 16 * mt + quad * 4) = pv;
      }
    }
    __asm__ volatile("s_waitcnt lgkmcnt(0)" ::: "memory");
    // O^T += V^T.P^T : A-frag = V^T rows (m=w=16mt+col), B-frag = P rows
#pragma unroll
    for (int kk = 0; kk < 2; kk++) {
      bf16x8 pf0 = *(const bf16x8*)(Pw + col * 72 + kk * 32 + quad * 8);
      bf16x8 pf1 = *(const bf16x8*)(Pw + (16 + col) * 72 + kk * 32 + quad * 8);
      const int vsw = ((kk * 4 + quad) ^ sw) << 3;
#pragma unroll
      for (int mt = 0; mt < 4; mt++) {
        const bf16x8 va = *(const bf16x8*)(Vlc + (16 * mt + col) * 64 + vsw);
        oacc[0][mt] = MFMA16(va, pf0, oacc[0][mt]);
        oacc[1][mt] = MFMA16(va, pf1, oacc[1][mt]);
      }
    }
  }
#undef STAGE

  // epilogue: lane holds O^T[w=16mt+quad*4+r][q=qg*16+col] -> fp32 dwordx4
#pragma unroll
  for (int qg = 0; qg < 2; qg++) {
    const float inv = 1.0f / lrow[qg];
    const int s = qbase + qg * 16 + col;
#pragma unroll
    for (int mt = 0; mt < 4; mt++) {
      f32x4 o;
#pragma unroll
      for (int r = 0; r < 4; r++) o[r] = oacc[qg][mt][r] * inv;
      *(f32x4*)(out + ((size_t)b * S_ + s) * D_ + h * 64 + 16 * mt + quad * 4) = o;
    }
  }
}

// ---------------------------------------------------------------------------
extern "C" void kernel_launch(void* const* d_in, const int* in_sizes, int n_in,
                              void* d_out, int out_size, void* d_ws, size_t ws_size,
                              hipStream_t stream) {
  const float* x  = (const float*)d_in[0];
  const int* mask = (const int*)d_in[1];
  const float* Wq = (const float*)d_in[2];
  const float* bq = (const float*)d_in[3];
  const float* Wk = (const float*)d_in[4];
  const float* bk = (const float*)d_in[5];
  const float* Wv = (const float*)d_in[6];
  const float* bv = (const float*)d_in[7];
  float* out = (float*)d_out;

  // d_out first half doubles as x-bf16 scratch; overwritten by attn at the end.
  __bf16* xb = (__bf16*)d_out;

  // ws: Q 16MB | K 16MB | V^T 16MB | Tq/Tk/Tv 3x2MB | bias 6KB
  // (max byte offset used: 56,629,248 — within the R3-proven ws bound)
  char* ws = (char*)d_ws;
  __bf16* Qw  = (__bf16*)(ws);
  __bf16* Kw  = (__bf16*)(ws + 16777216);
  __bf16* Vtw = (__bf16*)(ws + 2 * 16777216);
  __bf16* Tq  = (__bf16*)(ws + 3 * 16777216);
  __bf16* Tk  = Tq + 1024 * 1024;
  __bf16* Tv  = Tk + 1024 * 1024;
  __bf16* biasb = Tv + 1024 * 1024;

  convx<<<4096, 256, 0, stream>>>(x, xb);
  wtrans<<<dim3(16, 16, 3), 256, 0, stream>>>(Wq, Wk, Wv, Tq, Tk, Tv);
  convb<<<3, 256, 0, stream>>>(bq, bk, bv, biasb);
  qkv_gemm<<<dim3(8, 64, 3), 256, 0, stream>>>(xb, Tq, Tk, Tv, biasb, Qw, Kw, Vtw);
  attn<<<dim3(16, 64), 256, 0, stream>>>(Qw, Kw, Vtw, mask, out);
}

// Round 9
// 280.945 us; speedup vs baseline: 1.0807x; 1.0807x over previous
//
#include <hip/hip_runtime.h>

// Problem: B=4, S=2048, D=1024, H=16, W=64.
// Inputs fp32, output fp32; compute in bf16 MFMA.
#define B_ 4
#define S_ 2048
#define D_ 1024
#define H_ 16
#define W_ 64

typedef __attribute__((ext_vector_type(8))) __bf16 bf16x8;
typedef __attribute__((ext_vector_type(4))) __bf16 bf16x4;
typedef __attribute__((ext_vector_type(4))) float f32x4;

static __device__ __forceinline__ void gload_lds16(const void* g, void* l) {
  __builtin_amdgcn_global_load_lds((const __attribute__((address_space(1))) void*)g,
                                   (__attribute__((address_space(3))) void*)l,
                                   16, 0, 0);
}

#define MFMA16(a, b, c) __builtin_amdgcn_mfma_f32_16x16x32_bf16((a), (b), (c), 0, 0, 0)

// Raw v_exp_f32 (2^x). exp2f libcall carries non-fast-math range checks (R6 lesson).
#if __has_builtin(__builtin_amdgcn_exp2f)
#define EXP2(x) __builtin_amdgcn_exp2f(x)
#else
#define EXP2(x) __expf((x) * 0.6931472f)
#endif

// ---------------------------------------------------------------------------
// Kernel 1: convert x (fp32) -> bf16 scratch. 8 elems/thread.
// ---------------------------------------------------------------------------
__global__ __launch_bounds__(256) void convx(const float* __restrict__ x,
                                             __bf16* __restrict__ xb) {
  const size_t i = ((size_t)blockIdx.x * 256 + threadIdx.x) * 8;
  const f32x4 v0 = *(const f32x4*)(x + i);
  const f32x4 v1 = *(const f32x4*)(x + i + 4);
  bf16x8 v;
#pragma unroll
  for (int k = 0; k < 4; k++) { v[k] = (__bf16)v0[k]; v[4 + k] = (__bf16)v1[k]; }
  *(bf16x8*)(xb + i) = v;
}

// ---------------------------------------------------------------------------
// Kernel 2: weight transpose+convert W[k][n] (fp32) -> T[n][k] bf16
// ---------------------------------------------------------------------------
__global__ __launch_bounds__(256) void wtrans(
    const float* __restrict__ Wq, const float* __restrict__ Wk, const float* __restrict__ Wv,
    __bf16* __restrict__ Tq, __bf16* __restrict__ Tk, __bf16* __restrict__ Tv) {
  __shared__ __bf16 t[64][65];
  const int z = blockIdx.z;
  const float* W = (z == 0) ? Wq : (z == 1) ? Wk : Wv;
  __bf16* T = (z == 0) ? Tq : (z == 1) ? Tk : Tv;
  const int n0 = blockIdx.x * 64, k0 = blockIdx.y * 64;
  const int row = threadIdx.x >> 2, c0 = (threadIdx.x & 3) * 16;
#pragma unroll
  for (int i = 0; i < 16; i++)
    t[row][c0 + i] = (__bf16)W[(size_t)(k0 + row) * D_ + n0 + c0 + i];
  __syncthreads();
#pragma unroll
  for (int i = 0; i < 16; i++) T[(size_t)(n0 + row) * D_ + k0 + c0 + i] = t[c0 + i][row];
}

// ---------------------------------------------------------------------------
// Kernel 3: bias convert fp32 -> bf16 in ws (3 x 1024)
// ---------------------------------------------------------------------------
__global__ __launch_bounds__(256) void convb(
    const float* __restrict__ bq, const float* __restrict__ bk, const float* __restrict__ bv,
    __bf16* __restrict__ dst) {
  const int z = blockIdx.x;
  const float* src = (z == 0) ? bq : (z == 1) ? bk : bv;
  const int i = threadIdx.x * 4;
#pragma unroll
  for (int k = 0; k < 4; k++) dst[z * 1024 + i + k] = (__bf16)src[i + k];
}

// ---------------------------------------------------------------------------
// Kernel 4: fused QKV projection GEMM. BK=64 (16 K-iters, barrier drains
//   amortized over 32 MFMA — LDS 32KB keeps 3 blocks/CU, VGPR-bound anyway).
//   A/B LDS rows are 128B -> XOR-chunk swizzle (R3 lesson) keeps ds_read_b128
//   bank-uniform. Epilogue = R7's direct stores (R8's LDS epilogue regressed).
//   Q scaled by 0.125*log2(e); Q,K written [B,H,S,64]; V written [B,H,64,S].
// ---------------------------------------------------------------------------
__global__ __launch_bounds__(256) void qkv_gemm(
    const __bf16* __restrict__ x,
    const __bf16* __restrict__ Tq, const __bf16* __restrict__ Tk, const __bf16* __restrict__ Tv,
    const __bf16* __restrict__ biasb,
    __bf16* __restrict__ Qo, __bf16* __restrict__ Ko, __bf16* __restrict__ Vto) {
  __shared__ __align__(16) __bf16 As[128 * 64];  // [row][k], 128B rows, chunk-swizzled
  __shared__ __align__(16) __bf16 Bs[128 * 64];
  const int tid = threadIdx.x, lane = tid & 63;
  const int wid = tid >> 6, wm = wid >> 1, wn = wid & 1;
  const int quad = lane >> 4, col = lane & 15;
  const int sw = col & 7;
  const int n0 = blockIdx.x * 128, m0 = blockIdx.y * 128, z = blockIdx.z;
  const __bf16* Wt = (z == 0) ? Tq : (z == 1) ? Tk : Tv;
  const __bf16* bias = biasb + z * 1024;

  f32x4 acc[4][4] = {};

  // staging: thread's 16B chunk c=tid&7 of row r=(tid>>3)+32j; source chunk
  // swizzled c^(r&7) -> constant per-thread offset soff.
  const int srow = tid >> 3;
  const int soff = (((tid & 7) ^ ((tid >> 3) & 7)) << 4);

  for (int kt = 0; kt < D_ / 64; ++kt) {
    const int k0 = kt * 64;
    __syncthreads();
    const char* ax = (const char*)x + (size_t)(m0 + srow) * (D_ * 2) + k0 * 2 + soff;
    const char* bx = (const char*)Wt + (size_t)(n0 + srow) * (D_ * 2) + k0 * 2 + soff;
#pragma unroll
    for (int j = 0; j < 4; j++) {
      gload_lds16(ax + (size_t)j * 32 * (D_ * 2), (char*)As + tid * 16 + j * 4096);
      gload_lds16(bx + (size_t)j * 32 * (D_ * 2), (char*)Bs + tid * 16 + j * 4096);
    }
    __syncthreads();

#pragma unroll
    for (int kk = 0; kk < 2; kk++) {
      const int pc = (((kk << 2) + quad) ^ sw) << 3;  // physical chunk offset (elems)
      bf16x8 a[4], bb[4];
#pragma unroll
      for (int i = 0; i < 4; i++)
        a[i] = *(const bf16x8*)(As + (wm * 64 + 16 * i + col) * 64 + pc);
#pragma unroll
      for (int j = 0; j < 4; j++)
        bb[j] = *(const bf16x8*)(Bs + (wn * 64 + 16 * j + col) * 64 + pc);
#pragma unroll
      for (int i = 0; i < 4; i++)
#pragma unroll
        for (int j = 0; j < 4; j++) acc[i][j] = MFMA16(a[i], bb[j], acc[i][j]);
    }
  }

  // epilogue (R7 direct-store form). C/D layout: row = quad*4+r, col = lane&15
  const float scale = (z == 0) ? 0.18033688f : 1.0f;  // 0.125 * log2(e) for Q
#pragma unroll
  for (int j = 0; j < 4; j++) {
    const int n = n0 + wn * 64 + 16 * j + col;
    const float bval = (float)bias[n];
    const int h = n >> 6, w = n & 63;
#pragma unroll
    for (int i = 0; i < 4; i++) {
      const int m = m0 + wm * 64 + 16 * i + quad * 4;
      const int b = m >> 11, s = m & 2047;
      if (z < 2) {
        __bf16* outp = ((z == 0) ? Qo : Ko) + ((size_t)(b * H_ + h) * S_ + s) * W_ + w;
#pragma unroll
        for (int r = 0; r < 4; r++) outp[(size_t)r * W_] = (__bf16)((acc[i][j][r] + bval) * scale);
      } else {
        bf16x4 v;
#pragma unroll
        for (int r = 0; r < 4; r++) v[r] = (__bf16)(acc[i][j][r] + bval);
        *(bf16x4*)(Vto + ((size_t)(b * H_ + h) * W_ + w) * S_ + s) = v;
      }
    }
  }
}

// ---------------------------------------------------------------------------
// Kernel 5: flash attention (R7 proven version). S^T formulation, XOR-swizzled
//   K/V LDS, single-buffered staging, plain softmax via raw v_exp_f32.
//   Block = 128 q rows (4 waves x 32), 64-key tiles.
// ---------------------------------------------------------------------------
__global__ __launch_bounds__(256) void attn(
    const __bf16* __restrict__ Q, const __bf16* __restrict__ K,
    const __bf16* __restrict__ Vt, const int* __restrict__ mask,
    float* __restrict__ out) {
  __shared__ __align__(16) __bf16 Kl[64 * 64];     // [key][w], chunk-swizzled
  __shared__ __align__(16) __bf16 Vl[64 * 64];     // [w][key], chunk-swizzled
  __shared__ __align__(16) __bf16 Pl[4][32 * 72];  // per-wave P[q][key], stride 72
  __shared__ __align__(16) float Ml[64];           // additive mask * log2e
  __shared__ int Mflag;                            // 1 = tile mask all ones

  const int tid = threadIdx.x, lane = tid & 63, wid = tid >> 6;
  const int quad = lane >> 4, col = lane & 15;
  const int bh = blockIdx.y, b = bh >> 4, h = bh & 15;
  const int qbase = blockIdx.x * 128 + wid * 32;
  const int sw = col & 7;

  // Q B-fragments (lane n=col holds Q[q][k=quad*8+j], kk chunks): qf[qg][kk]
  bf16x8 qf[2][2];
#pragma unroll
  for (int qg = 0; qg < 2; qg++) {
    const __bf16* qp = Q + ((size_t)bh * S_ + qbase + qg * 16 + col) * W_ + quad * 8;
    qf[qg][0] = *(const bf16x8*)qp;
    qf[qg][1] = *(const bf16x8*)(qp + 32);
  }

  f32x4 oacc[2][4] = {};
  float lrow[2] = {0.f, 0.f};

  // staging lanes: flat f -> row r (128B), chunk c; fetch global chunk c^(r&7)
  const int f1 = tid * 16, r1 = f1 >> 7, c1 = (f1 >> 4) & 7;
  const int f2 = f1 + 4096, r2 = f2 >> 7, c2 = (f2 >> 4) & 7;
  const int s1 = (c1 ^ (r1 & 7)) << 4, s2 = (c2 ^ (r2 & 7)) << 4;

  __bf16* Pw = Pl[wid];

  for (int kt = 0; kt < S_ / 64; ++kt) {
    const int k0 = kt * 64;
    __syncthreads();
    const char* kg = (const char*)(K + ((size_t)bh * S_ + k0) * W_);
    gload_lds16(kg + (size_t)r1 * 128 + s1, (char*)Kl + f1);
    gload_lds16(kg + (size_t)r2 * 128 + s2, (char*)Kl + f2);
    const char* vg = (const char*)(Vt + (size_t)bh * W_ * S_ + k0);
    gload_lds16(vg + (size_t)r1 * (S_ * 2) + s1, (char*)Vl + f1);
    gload_lds16(vg + (size_t)r2 * (S_ * 2) + s2, (char*)Vl + f2);
    if (tid < 64) {  // wave 0 stages mask + all-ones ballot
      const int m = mask[b * S_ + k0 + tid];
      Ml[tid] = -14426.95f * (1.0f - (float)m);  // -10000*log2e
      const unsigned long long bal = __ballot(m != 0);
      if (tid == 0) Mflag = (~bal == 0ull) ? 1 : 0;
    }
    __syncthreads();

    // St = K.Q^T : A-frag = K rows (m=key=16mt+col), B-frag = qf
    f32x4 sacc[2][4] = {};
#pragma unroll
    for (int mt = 0; mt < 4; mt++) {
      const __bf16* kr = Kl + (16 * mt + col) * 64;
      const bf16x8 ka0 = *(const bf16x8*)(kr + ((quad ^ sw) << 3));
      const bf16x8 ka1 = *(const bf16x8*)(kr + (((4 + quad) ^ sw) << 3));
#pragma unroll
      for (int qg = 0; qg < 2; qg++) {
        sacc[qg][mt] = MFMA16(ka0, qf[qg][0], sacc[qg][mt]);
        sacc[qg][mt] = MFMA16(ka1, qf[qg][1], sacc[qg][mt]);
      }
    }
    // additive mask only when some key is masked (wave-uniform branch)
    const int allone = __builtin_amdgcn_readfirstlane(Mflag);
    if (!allone) {
      f32x4 mAdd[4];
#pragma unroll
      for (int mt = 0; mt < 4; mt++) mAdd[mt] = *(const f32x4*)(Ml + 16 * mt + quad * 4);
#pragma unroll
      for (int qg = 0; qg < 2; qg++)
#pragma unroll
        for (int mt = 0; mt < 4; mt++)
#pragma unroll
          for (int r = 0; r < 4; r++) sacc[qg][mt][r] += mAdd[mt][r];
    }

    // plain softmax partial: p = exp2(s') via raw v_exp_f32; vector l-sum
#pragma unroll
    for (int qg = 0; qg < 2; qg++) {
      f32x4 vsum = {0.f, 0.f, 0.f, 0.f};
#pragma unroll
      for (int mt = 0; mt < 4; mt++) {
#pragma unroll
        for (int r = 0; r < 4; r++) sacc[qg][mt][r] = EXP2(sacc[qg][mt][r]);
        vsum += sacc[qg][mt];
      }
      float sum = (vsum[0] + vsum[1]) + (vsum[2] + vsum[3]);
      sum += __shfl_xor(sum, 16, 64);
      sum += __shfl_xor(sum, 32, 64);
      lrow[qg] += sum;
      // P[q][key]: 4 consecutive keys per (mt) -> ds_write_b64
#pragma unroll
      for (int mt = 0; mt < 4; mt++) {
        bf16x4 pv;
#pragma unroll
        for (int r = 0; r < 4; r++) pv[r] = (__bf16)sacc[qg][mt][r];
        *(bf16x4*)(Pw + (qg * 16 + col) * 72 + 16 * mt + quad * 4) = pv;
      }
    }
    __asm__ volatile("s_waitcnt lgkmcnt(0)" ::: "memory");
    // O^T += V^T.P^T : A-frag = V^T rows (m=w=16mt+col), B-frag = P rows
#pragma unroll
    for (int kk = 0; kk < 2; kk++) {
      bf16x8 pf0 = *(const bf16x8*)(Pw + col * 72 + kk * 32 + quad * 8);
      bf16x8 pf1 = *(const bf16x8*)(Pw + (16 + col) * 72 + kk * 32 + quad * 8);
      const int vsw = ((kk * 4 + quad) ^ sw) << 3;
#pragma unroll
      for (int mt = 0; mt < 4; mt++) {
        const bf16x8 va = *(const bf16x8*)(Vl + (16 * mt + col) * 64 + vsw);
        oacc[0][mt] = MFMA16(va, pf0, oacc[0][mt]);
        oacc[1][mt] = MFMA16(va, pf1, oacc[1][mt]);
      }
    }
  }

  // epilogue: lane holds O^T[w=16mt+quad*4+r][q=qg*16+col] -> fp32 dwordx4
#pragma unroll
  for (int qg = 0; qg < 2; qg++) {
    const float inv = 1.0f / lrow[qg];
    const int s = qbase + qg * 16 + col;
#pragma unroll
    for (int mt = 0; mt < 4; mt++) {
      f32x4 o;
#pragma unroll
      for (int r = 0; r < 4; r++) o[r] = oacc[qg][mt][r] * inv;
      *(f32x4*)(out + ((size_t)b * S_ + s) * D_ + h * 64 + 16 * mt + quad * 4) = o;
    }
  }
}

// ---------------------------------------------------------------------------
extern "C" void kernel_launch(void* const* d_in, const int* in_sizes, int n_in,
                              void* d_out, int out_size, void* d_ws, size_t ws_size,
                              hipStream_t stream) {
  const float* x  = (const float*)d_in[0];
  const int* mask = (const int*)d_in[1];
  const float* Wq = (const float*)d_in[2];
  const float* bq = (const float*)d_in[3];
  const float* Wk = (const float*)d_in[4];
  const float* bk = (const float*)d_in[5];
  const float* Wv = (const float*)d_in[6];
  const float* bv = (const float*)d_in[7];
  float* out = (float*)d_out;

  // d_out first half doubles as x-bf16 scratch; overwritten by attn at the end.
  __bf16* xb = (__bf16*)d_out;

  // ws: Q 16MB | K 16MB | V^T 16MB | Tq/Tk/Tv 3x2MB | bias 6KB
  // (max byte offset used: 56,629,248 — within the R3-proven ws bound)
  char* ws = (char*)d_ws;
  __bf16* Qw  = (__bf16*)(ws);
  __bf16* Kw  = (__bf16*)(ws + 16777216);
  __bf16* Vtw = (__bf16*)(ws + 2 * 16777216);
  __bf16* Tq  = (__bf16*)(ws + 3 * 16777216);
  __bf16* Tk  = Tq + 1024 * 1024;
  __bf16* Tv  = Tk + 1024 * 1024;
  __bf16* biasb = Tv + 1024 * 1024;

  convx<<<4096, 256, 0, stream>>>(x, xb);
  wtrans<<<dim3(16, 16, 3), 256, 0, stream>>>(Wq, Wk, Wv, Tq, Tk, Tv);
  convb<<<3, 256, 0, stream>>>(bq, bk, bv, biasb);
  qkv_gemm<<<dim3(8, 64, 3), 256, 0, stream>>>(xb, Tq, Tk, Tv, biasb, Qw, Kw, Vtw);
  attn<<<dim3(16, 64), 256, 0, stream>>>(Qw, Kw, Vtw, mask, out);
}